// Round 1
// baseline (1277.483 us; speedup 1.0000x reference)
//
#include <hip/hip_runtime.h>
#include <hip/hip_bf16.h>

// Double Attention (A^2-Net), fp32 baseline.
// B=16, H=W=64, C=512, DIM=VDIM=256, N=4096.
//
// Pipeline:
//  1) q = x@Wq+bq, k = x@Wk+bk, v = x@Wv+bv          (sgemm_nn x3)
//  2) ksm = softmax_n(k), vsm = softmax_n(v) in place (3 small kernels)
//  3) G[b] = ksm[b]^T @ q[b]                          (gemm_tn)
//  4) GW[b] = G[b] @ Wr                               (sgemm_nn batched)
//  5) out[b] = vsm[b] @ GW[b] + br                    (sgemm_nn batched, fused
//     reconstruct: (av@G)@Wr == av@(G@Wr))

#define BATCH 16
#define NPOS 4096            // H*W
#define CDIM 512
#define DDIM 256             // DIM
#define VDIM 256
#define MTOT (BATCH * NPOS)  // 65536
#define NCHUNK 32
#define ROWS (NPOS / NCHUNK) // 128

// ---------------------------------------------------------------------------
// Generic fp32 NN GEMM: C[M,N] = A[M,K] @ B[K,N] (+bias), row-major, batched
// via blockIdx.z strides. 128x128 tile, BK=8, 256 threads, 8x8 per thread.
// Split-4 column/row mapping keeps ds_read_b128 at <=2-way bank aliasing.
// Requires M%128==0, N%128==0, K%8==0.
// ---------------------------------------------------------------------------
__global__ __launch_bounds__(256) void sgemm_nn(
    const float* __restrict__ A, const float* __restrict__ Bm,
    const float* __restrict__ bias, float* __restrict__ Cm,
    int M, int N, int K, long sA, long sB, long sC)
{
    const int b = blockIdx.z;
    A  += (size_t)b * sA;
    Bm += (size_t)b * sB;
    Cm += (size_t)b * sC;
    const int m0 = blockIdx.y * 128;
    const int n0 = blockIdx.x * 128;

    __shared__ float As[8][128];   // transposed: As[k][m]
    __shared__ float Bs[8][128];   // Bs[k][n]

    const int tid = threadIdx.x;
    const int ar  = tid >> 1;            // 0..127 (A row within tile)
    const int ac  = (tid & 1) * 4;       // 0 or 4 (A k-offset)
    const int brr = tid >> 5;            // 0..7   (B k-row)
    const int bc  = (tid & 31) * 4;      // 0..124 (B col)
    const int tx  = tid & 15;
    const int ty  = tid >> 4;

    float acc[8][8] = {};

    const float* Aptr = A + (size_t)(m0 + ar) * K + ac;
    const float* Bptr = Bm + (size_t)brr * N + n0 + bc;

    for (int k0 = 0; k0 < K; k0 += 8) {
        float4 a   = *(const float4*)(Aptr);
        float4 bv4 = *(const float4*)(Bptr);
        __syncthreads();
        As[ac + 0][ar] = a.x;
        As[ac + 1][ar] = a.y;
        As[ac + 2][ar] = a.z;
        As[ac + 3][ar] = a.w;
        *(float4*)&Bs[brr][bc] = bv4;
        __syncthreads();
#pragma unroll
        for (int kk = 0; kk < 8; ++kk) {
            float4 a0 = *(const float4*)&As[kk][ty * 4];
            float4 a1 = *(const float4*)&As[kk][64 + ty * 4];
            float4 b0 = *(const float4*)&Bs[kk][tx * 4];
            float4 b1 = *(const float4*)&Bs[kk][64 + tx * 4];
            float arr[8] = {a0.x, a0.y, a0.z, a0.w, a1.x, a1.y, a1.z, a1.w};
            float brw[8] = {b0.x, b0.y, b0.z, b0.w, b1.x, b1.y, b1.z, b1.w};
#pragma unroll
            for (int i = 0; i < 8; ++i)
#pragma unroll
                for (int j = 0; j < 8; ++j)
                    acc[i][j] = fmaf(arr[i], brw[j], acc[i][j]);
        }
        Aptr += 8;
        Bptr += (size_t)8 * N;
    }

    float4 bi0 = make_float4(0.f, 0.f, 0.f, 0.f);
    float4 bi1 = bi0;
    if (bias) {
        bi0 = *(const float4*)&bias[n0 + tx * 4];
        bi1 = *(const float4*)&bias[n0 + 64 + tx * 4];
    }
#pragma unroll
    for (int i = 0; i < 8; ++i) {
        const int ri = (i < 4) ? (ty * 4 + i) : (64 + ty * 4 + (i - 4));
        float* crow = Cm + (size_t)(m0 + ri) * N + n0;
        float4 o0 = make_float4(acc[i][0] + bi0.x, acc[i][1] + bi0.y,
                                acc[i][2] + bi0.z, acc[i][3] + bi0.w);
        float4 o1 = make_float4(acc[i][4] + bi1.x, acc[i][5] + bi1.y,
                                acc[i][6] + bi1.z, acc[i][7] + bi1.w);
        *(float4*)(crow + tx * 4)      = o0;
        *(float4*)(crow + 64 + tx * 4) = o1;
    }
}

// ---------------------------------------------------------------------------
// TN GEMM for G[b] = ksm[b]^T @ q[b] : G[v,d] = sum_n A[n,v]*B[n,d], K=NPOS.
// 64x64 tile, BK=32, 256 threads, 4x4 per thread.
// ---------------------------------------------------------------------------
__global__ __launch_bounds__(256) void gemm_tn(
    const float* __restrict__ Am, const float* __restrict__ Bq,
    float* __restrict__ Gout)
{
    const int b = blockIdx.z;
    const float* A  = Am + (size_t)b * NPOS * VDIM;
    const float* Bb = Bq + (size_t)b * NPOS * DDIM;
    float* Gp = Gout + (size_t)b * VDIM * DDIM;
    const int v0 = blockIdx.y * 64;
    const int d0 = blockIdx.x * 64;

    __shared__ float As[32][64];
    __shared__ float Bs[32][64];

    const int tid = threadIdx.x;
    const int lr = tid >> 4;          // 0..15
    const int lc = (tid & 15) * 4;    // 0..60
    const int tx = tid & 15;
    const int ty = tid >> 4;

    float acc[4][4] = {};

    for (int n0 = 0; n0 < NPOS; n0 += 32) {
        float4 a0 = *(const float4*)(A + (size_t)(n0 + lr) * VDIM + v0 + lc);
        float4 a1 = *(const float4*)(A + (size_t)(n0 + lr + 16) * VDIM + v0 + lc);
        float4 b0 = *(const float4*)(Bb + (size_t)(n0 + lr) * DDIM + d0 + lc);
        float4 b1 = *(const float4*)(Bb + (size_t)(n0 + lr + 16) * DDIM + d0 + lc);
        __syncthreads();
        *(float4*)&As[lr][lc]      = a0;
        *(float4*)&As[lr + 16][lc] = a1;
        *(float4*)&Bs[lr][lc]      = b0;
        *(float4*)&Bs[lr + 16][lc] = b1;
        __syncthreads();
#pragma unroll
        for (int kk = 0; kk < 32; ++kk) {
            float4 a  = *(const float4*)&As[kk][ty * 4];
            float4 bb = *(const float4*)&Bs[kk][tx * 4];
            float av_[4] = {a.x, a.y, a.z, a.w};
            float bv_[4] = {bb.x, bb.y, bb.z, bb.w};
#pragma unroll
            for (int i = 0; i < 4; ++i)
#pragma unroll
                for (int j = 0; j < 4; ++j)
                    acc[i][j] = fmaf(av_[i], bv_[j], acc[i][j]);
        }
    }
#pragma unroll
    for (int i = 0; i < 4; ++i) {
        float* grow = Gp + (size_t)(v0 + ty * 4 + i) * DDIM + d0;
        float4 o = make_float4(acc[i][0], acc[i][1], acc[i][2], acc[i][3]);
        *(float4*)(grow + tx * 4) = o;
    }
}

// ---------------------------------------------------------------------------
// Column softmax over n (axis=1) for k and v, [B][N][256] each.
// 3-phase: per-chunk online max/sum -> combine -> normalize write.
// ---------------------------------------------------------------------------
__global__ __launch_bounds__(256) void sm_partial(
    const float* __restrict__ ksm, const float* __restrict__ vsm,
    float* __restrict__ pmax, float* __restrict__ psum)
{
    const int z = blockIdx.z, b = blockIdx.y, chunk = blockIdx.x;
    const int ch = threadIdx.x;
    const float* T = (z == 0 ? ksm : vsm) +
                     ((size_t)b * NPOS + (size_t)chunk * ROWS) * VDIM + ch;
    float m = -3.4e38f, s = 0.f;
    for (int r = 0; r < ROWS; ++r) {
        float x = T[(size_t)r * VDIM];
        float nm = fmaxf(m, x);
        s = s * __expf(m - nm) + __expf(x - nm);
        m = nm;
    }
    const size_t idx = (((size_t)z * BATCH + b) * NCHUNK + chunk) * VDIM + ch;
    pmax[idx] = m;
    psum[idx] = s;
}

__global__ __launch_bounds__(256) void sm_combine(
    const float* __restrict__ pmax, const float* __restrict__ psum,
    float* __restrict__ gmax, float* __restrict__ ginv)
{
    const int z = blockIdx.y, b = blockIdx.x, ch = threadIdx.x;
    const size_t base = (((size_t)z * BATCH + b) * NCHUNK) * VDIM + ch;
    float M = -3.4e38f;
    for (int c = 0; c < NCHUNK; ++c)
        M = fmaxf(M, pmax[base + (size_t)c * VDIM]);
    float s = 0.f;
    for (int c = 0; c < NCHUNK; ++c)
        s += psum[base + (size_t)c * VDIM] * __expf(pmax[base + (size_t)c * VDIM] - M);
    const size_t gi = ((size_t)z * BATCH + b) * VDIM + ch;
    gmax[gi] = M;
    ginv[gi] = 1.f / s;
}

__global__ __launch_bounds__(256) void sm_write(
    float* __restrict__ ksm, float* __restrict__ vsm,
    const float* __restrict__ gmax, const float* __restrict__ ginv)
{
    const int z = blockIdx.z, b = blockIdx.y, chunk = blockIdx.x;
    const int ch = threadIdx.x;
    float* T = (z == 0 ? ksm : vsm) +
               ((size_t)b * NPOS + (size_t)chunk * ROWS) * VDIM + ch;
    const size_t gi = ((size_t)z * BATCH + b) * VDIM + ch;
    const float M = gmax[gi], R = ginv[gi];
    for (int r = 0; r < ROWS; ++r) {
        float x = T[(size_t)r * VDIM];
        T[(size_t)r * VDIM] = __expf(x - M) * R;
    }
}

// ---------------------------------------------------------------------------
extern "C" void kernel_launch(void* const* d_in, const int* in_sizes, int n_in,
                              void* d_out, int out_size, void* d_ws, size_t ws_size,
                              hipStream_t stream)
{
    const float* x  = (const float*)d_in[0];
    const float* Wq = (const float*)d_in[1];
    const float* bq = (const float*)d_in[2];
    const float* Wk = (const float*)d_in[3];
    const float* bk = (const float*)d_in[4];
    const float* Wv = (const float*)d_in[5];
    const float* bv = (const float*)d_in[6];
    const float* Wr = (const float*)d_in[7];
    const float* br = (const float*)d_in[8];
    float* out = (float*)d_out;

    // Workspace layout (floats). Total ~54M floats (~215 MB).
    float* q    = (float*)d_ws;
    float* ksm  = q    + (size_t)MTOT * DDIM;
    float* vsm  = ksm  + (size_t)MTOT * VDIM;
    float* G    = vsm  + (size_t)MTOT * VDIM;
    float* GW   = G    + (size_t)BATCH * VDIM * DDIM;
    float* pmax = GW   + (size_t)BATCH * VDIM * CDIM;
    float* psum = pmax + (size_t)2 * BATCH * NCHUNK * VDIM;
    float* gmax = psum + (size_t)2 * BATCH * NCHUNK * VDIM;
    float* ginv = gmax + (size_t)2 * BATCH * VDIM;

    const dim3 blk(256);

    // 1) projections: q/k/v = x @ W* + b*   (M=65536, N=256, K=512)
    sgemm_nn<<<dim3(DDIM / 128, MTOT / 128, 1), blk, 0, stream>>>(
        x, Wq, bq, q, MTOT, DDIM, CDIM, 0, 0, 0);
    sgemm_nn<<<dim3(VDIM / 128, MTOT / 128, 1), blk, 0, stream>>>(
        x, Wk, bk, ksm, MTOT, VDIM, CDIM, 0, 0, 0);
    sgemm_nn<<<dim3(VDIM / 128, MTOT / 128, 1), blk, 0, stream>>>(
        x, Wv, bv, vsm, MTOT, VDIM, CDIM, 0, 0, 0);

    // 2) softmax over positions, in place on ksm and vsm
    sm_partial<<<dim3(NCHUNK, BATCH, 2), blk, 0, stream>>>(ksm, vsm, pmax, psum);
    sm_combine<<<dim3(BATCH, 2), blk, 0, stream>>>(pmax, psum, gmax, ginv);
    sm_write<<<dim3(NCHUNK, BATCH, 2), blk, 0, stream>>>(ksm, vsm, gmax, ginv);

    // 3) G[b] = ksm[b]^T @ q[b]   ([256,4096]x[4096,256] per batch)
    gemm_tn<<<dim3(DDIM / 64, VDIM / 64, BATCH), blk, 0, stream>>>(ksm, q, G);

    // 4) GW[b] = G[b] @ Wr   (M=256, N=512, K=256)
    sgemm_nn<<<dim3(CDIM / 128, VDIM / 128, BATCH), blk, 0, stream>>>(
        G, Wr, nullptr, GW, VDIM, CDIM, DDIM,
        (long)VDIM * DDIM, 0, (long)VDIM * CDIM);

    // 5) out[b] = vsm[b] @ GW[b] + br   (M=4096, N=512, K=256)
    sgemm_nn<<<dim3(CDIM / 128, NPOS / 128, BATCH), blk, 0, stream>>>(
        vsm, GW, br, out, NPOS, CDIM, VDIM,
        (long)NPOS * VDIM, (long)VDIM * CDIM, (long)NPOS * CDIM);
}

// Round 2
// 464.568 us; speedup vs baseline: 2.7498x; 2.7498x over previous
//
#include <hip/hip_runtime.h>

// Double Attention (A^2-Net), bf16-MFMA version.
// B=16, H=W=64, C=512, DIM=VDIM=256, N=4096.
//
// Pipeline (all GEMMs = mfma_f32_16x16x32_bf16, 128x128 tile, BK=32,
// global_load_lds width-16 staging, A'[M][K] / B'[N][K] both K-contiguous):
//  0) cast x -> xb (bf16); build WqkvT[768][512], WrT[512][256], bqkv (bf16/f32)
//  1) proj: [65536,512]@[512,768] -> qT[b][256][4096], kT[b][256][4096] (LDS
//     transpose epilogue), vb[65536][256]
//  2) ksoftmax: row softmax over n on kT in place
//     vsoftmax: 3-phase column softmax over n on vb in place
//  3) g_gemm (split-K=8): Gpart[z][256][256] = kT[b]@qT[b]^T chunk sums
//     greduce: Gb[b][256][256] (bf16)
//  4) gwT: GWT[b][512][256] = (Wr^T) @ Gb^T  (== (G@Wr)^T)
//  5) out:  out[65536][512] = vsm @ GWT[b]^T + br   (fused reconstruct)

#define BATCH 16
#define NPOS 4096
#define CDIM 512
#define DDIM 256
#define MTOT (BATCH * NPOS)

typedef unsigned short u16;
typedef __attribute__((ext_vector_type(4))) unsigned short u16x4;
typedef __attribute__((ext_vector_type(8))) unsigned short u16x8;
typedef __attribute__((ext_vector_type(8))) short s16x8;
typedef __attribute__((ext_vector_type(4))) float f32x4;

__device__ __forceinline__ u16 f2bf(float f) {
    union { float f; unsigned u; } v; v.f = f;
    unsigned u = v.u;
    unsigned r = (u + 0x7fffu + ((u >> 16) & 1u)) >> 16;
    return (u16)r;
}
__device__ __forceinline__ float bf2f(u16 h) {
    union { unsigned u; float f; } v; v.u = ((unsigned)h) << 16;
    return v.f;
}

// async global->LDS, 16B per lane; lds base must be wave-uniform (dest =
// base + lane*16, per guide m97/m104).
__device__ __forceinline__ void gload_lds16(const u16* g, u16* l) {
    __builtin_amdgcn_global_load_lds(
        (const __attribute__((address_space(1))) void*)g,
        (__attribute__((address_space(3))) void*)l, 16, 0, 0);
}

// ---------------------------------------------------------------------------
// Core 128x128 bf16 MFMA tile loop. A'[*, lda] rows m0..m0+127,
// B'[*, ldb] rows n0..n0+127, contraction k = koff .. koff + 32*ksteps.
// LDS: As/Bs 8KB each, row-major [128][32] bf16, linear (gload_lds friendly).
// 4 waves (2x2), each wave 64x64 = 4x4 frags of 16x16x32.
// ---------------------------------------------------------------------------
__device__ __forceinline__ void gemm_core(
    const u16* __restrict__ A, int lda,
    const u16* __restrict__ B, int ldb,
    int m0, int n0, long koff, int ksteps,
    u16* As, u16* Bs, f32x4 (&acc)[4][4])
{
    const int tid  = threadIdx.x;
    const int lane = tid & 63;
    const int wave = tid >> 6;
    const int wm = wave >> 1, wn = wave & 1;
    const int fr = lane & 15;
    const int kq = lane >> 4;

    const int srow = lane >> 2;   // staging: row within 16-row group
    const int skq  = lane & 3;    // staging: k-quarter (8 bf16 = 16B)

    const u16* Arow0 = A + (size_t)(m0 + wave * 16 + srow) * lda + koff + skq * 8;
    const u16* Arow1 = A + (size_t)(m0 + 64 + wave * 16 + srow) * lda + koff + skq * 8;
    const u16* Brow0 = B + (size_t)(n0 + wave * 16 + srow) * ldb + koff + skq * 8;
    const u16* Brow1 = B + (size_t)(n0 + 64 + wave * 16 + srow) * ldb + koff + skq * 8;

    u16* AsW0 = As + wave * 512;          // bytes: wave*1024
    u16* AsW1 = As + 2048 + wave * 512;   // second 64 rows
    u16* BsW0 = Bs + wave * 512;
    u16* BsW1 = Bs + 2048 + wave * 512;

    for (int ks = 0; ks < ksteps; ++ks) {
        const size_t ko = (size_t)ks * 32;
        __syncthreads();                  // prior reads done before overwrite
        gload_lds16(Arow0 + ko, AsW0);
        gload_lds16(Arow1 + ko, AsW1);
        gload_lds16(Brow0 + ko, BsW0);
        gload_lds16(Brow1 + ko, BsW1);
        __syncthreads();                  // compiler drains vmcnt(0) before barrier

        s16x8 aF[4], bF[4];
#pragma unroll
        for (int i = 0; i < 4; ++i)
            aF[i] = *(const s16x8*)(As + (size_t)(wm * 64 + i * 16 + fr) * 32 + kq * 8);
#pragma unroll
        for (int j = 0; j < 4; ++j)
            bF[j] = *(const s16x8*)(Bs + (size_t)(wn * 64 + j * 16 + fr) * 32 + kq * 8);
#pragma unroll
        for (int i = 0; i < 4; ++i)
#pragma unroll
            for (int j = 0; j < 4; ++j)
                acc[i][j] = __builtin_amdgcn_mfma_f32_16x16x32_bf16(
                    aF[i], bF[j], acc[i][j], 0, 0, 0);
    }
}

// ---------------------------------------------------------------------------
// 0) casts
// ---------------------------------------------------------------------------
__global__ __launch_bounds__(256) void cast_x(const float* __restrict__ x,
                                              u16* __restrict__ xb, int n4)
{
    int i = blockIdx.x * 256 + threadIdx.x;
    const int stride = gridDim.x * 256;
    for (; i < n4; i += stride) {
        float4 f = ((const float4*)x)[i];
        u16x4 o = { f2bf(f.x), f2bf(f.y), f2bf(f.z), f2bf(f.w) };
        ((u16x4*)xb)[i] = o;
    }
}

__global__ __launch_bounds__(256) void cast_w(
    const float* __restrict__ Wq, const float* __restrict__ Wk,
    const float* __restrict__ Wv, const float* __restrict__ bq,
    const float* __restrict__ bk, const float* __restrict__ bv,
    const float* __restrict__ Wr,
    u16* __restrict__ WqkvT, u16* __restrict__ WrT, float* __restrict__ bqkv)
{
    const int i0 = blockIdx.x * 256 + threadIdx.x;
    const int stride = gridDim.x * 256;
    for (int idx = i0; idx < 768 * 512; idx += stride) {   // WqkvT[nc][k] = W*[k][nc%256]
        int nc = idx >> 9, kk = idx & 511;
        const float* W = (nc < 256) ? Wq : (nc < 512) ? Wk : Wv;
        WqkvT[idx] = f2bf(W[(size_t)kk * 256 + (nc & 255)]);
    }
    for (int idx = i0; idx < 512 * 256; idx += stride) {   // WrT[c][d] = Wr[d][c]
        int c = idx >> 8, d = idx & 255;
        WrT[idx] = f2bf(Wr[(size_t)d * 512 + c]);
    }
    for (int idx = i0; idx < 768; idx += stride)
        bqkv[idx] = (idx < 256) ? bq[idx] : (idx < 512) ? bk[idx - 256] : bv[idx - 512];
}

// ---------------------------------------------------------------------------
// 1) fused QKV projection. grid (6, 512): n0 = bx*128 (0..767), m0 = by*128.
//    bx>>1: 0 -> qT (transpose epi), 1 -> kT (transpose epi), 2 -> vb (direct).
// ---------------------------------------------------------------------------
__global__ __launch_bounds__(256) void proj_qkv(
    const u16* __restrict__ xb, const u16* __restrict__ WqkvT,
    const float* __restrict__ bqkv,
    u16* __restrict__ qT, u16* __restrict__ kT, u16* __restrict__ vb)
{
    __shared__ u16 smem[18432];   // 36 KB: staging 16KB, then 4x 64x72 Ts
    u16* As = smem;
    u16* Bs = smem + 4096;

    const int bx = blockIdx.x;
    const int n0 = bx * 128;
    const int m0 = blockIdx.y * 128;

    f32x4 acc[4][4];
#pragma unroll
    for (int i = 0; i < 4; ++i)
#pragma unroll
        for (int j = 0; j < 4; ++j) acc[i][j] = (f32x4){0.f, 0.f, 0.f, 0.f};

    gemm_core(xb, 512, WqkvT, 512, m0, n0, 0, 16, As, Bs, acc);

    const int tid = threadIdx.x, lane = tid & 63, wave = tid >> 6;
    const int wm = wave >> 1, wn = wave & 1, fr = lane & 15, kq = lane >> 4;
    const int mode = bx >> 1;
    const int nl0 = (bx & 1) * 128;

    if (mode == 2) {              // v: direct [n][v] bf16 store
#pragma unroll
        for (int i = 0; i < 4; ++i)
#pragma unroll
            for (int j = 0; j < 4; ++j) {
                const int col = wn * 64 + j * 16 + fr;
                const float bias = bqkv[n0 + col];
#pragma unroll
                for (int r = 0; r < 4; ++r) {
                    const int row = wm * 64 + i * 16 + kq * 4 + r;
                    vb[(size_t)(m0 + row) * 256 + nl0 + col] = f2bf(acc[i][j][r] + bias);
                }
            }
        return;
    }

    // q/k: LDS-bounce transpose -> [channel][n] layout
    __syncthreads();                         // done with As/Bs, reuse as Ts
    u16* Ts = smem + wave * 4608;            // per-wave 64x72 (pad 8 vs bank)
#pragma unroll
    for (int i = 0; i < 4; ++i)
#pragma unroll
        for (int j = 0; j < 4; ++j) {
            const int colw = j * 16 + fr;
            const float bias = bqkv[n0 + wn * 64 + colw];
#pragma unroll
            for (int r = 0; r < 4; ++r) {
                const int roww = i * 16 + kq * 4 + r;
                Ts[roww * 72 + colw] = f2bf(acc[i][j][r] + bias);
            }
        }
    __syncthreads();

    u16* dstT = (mode == 0) ? qT : kT;
    const int b = m0 >> 12;
    const int nbase = (m0 & 4095) + wm * 64;
    const int dch = nl0 + wn * 64 + lane;    // lane picks a column of wave tile
    u16* dst = dstT + (size_t)b * (256 * 4096) + (size_t)dch * 4096 + nbase;
#pragma unroll
    for (int g = 0; g < 8; ++g) {
        u16x8 pack;
#pragma unroll
        for (int e = 0; e < 8; ++e)
            pack[e] = Ts[(g * 8 + e) * 72 + lane];
        *(u16x8*)(dst + g * 8) = pack;
    }
}

// ---------------------------------------------------------------------------
// 2a) row softmax on kT (softmax over n == rows of kT). grid 4096 blocks.
// ---------------------------------------------------------------------------
__global__ __launch_bounds__(256) void ksoftmax(u16* __restrict__ kT)
{
    u16* row = kT + (size_t)blockIdx.x * 4096;
    const int t = threadIdx.x, lane = t & 63, wave = t >> 6;
    __shared__ float red[4];

    float x[16];
    u16x8 u0 = *(const u16x8*)(row + t * 16);
    u16x8 u1 = *(const u16x8*)(row + t * 16 + 8);
#pragma unroll
    for (int e = 0; e < 8; ++e) { x[e] = bf2f(u0[e]); x[8 + e] = bf2f(u1[e]); }

    float m = -3.4e38f;
#pragma unroll
    for (int e = 0; e < 16; ++e) m = fmaxf(m, x[e]);
    for (int off = 32; off; off >>= 1) m = fmaxf(m, __shfl_xor(m, off));
    if (lane == 0) red[wave] = m;
    __syncthreads();
    const float M = fmaxf(fmaxf(red[0], red[1]), fmaxf(red[2], red[3]));
    __syncthreads();

    float s = 0.f;
#pragma unroll
    for (int e = 0; e < 16; ++e) { x[e] = __expf(x[e] - M); s += x[e]; }
    for (int off = 32; off; off >>= 1) s += __shfl_xor(s, off);
    if (lane == 0) red[wave] = s;
    __syncthreads();
    const float inv = 1.f / (red[0] + red[1] + red[2] + red[3]);

    u16x8 o0, o1;
#pragma unroll
    for (int e = 0; e < 8; ++e) { o0[e] = f2bf(x[e] * inv); o1[e] = f2bf(x[8 + e] * inv); }
    *(u16x8*)(row + t * 16) = o0;
    *(u16x8*)(row + t * 16 + 8) = o1;
}

// ---------------------------------------------------------------------------
// 2b) column softmax on vb (3-phase). grids (32,16) / (16) / (32,16).
// ---------------------------------------------------------------------------
__global__ __launch_bounds__(256) void vsm_partial(
    const u16* __restrict__ vb, float* __restrict__ pmax, float* __restrict__ psum)
{
    const int b = blockIdx.y, chunk = blockIdx.x, ch = threadIdx.x;
    const u16* T = vb + ((size_t)b * 4096 + (size_t)chunk * 128) * 256 + ch;
    float m = -3.4e38f, s = 0.f;
    for (int r = 0; r < 128; ++r) {
        float x = bf2f(T[(size_t)r * 256]);
        float nm = fmaxf(m, x);
        s = s * __expf(m - nm) + __expf(x - nm);
        m = nm;
    }
    const size_t idx = ((size_t)b * 32 + chunk) * 256 + ch;
    pmax[idx] = m; psum[idx] = s;
}

__global__ __launch_bounds__(256) void vsm_combine(
    const float* __restrict__ pmax, const float* __restrict__ psum,
    float* __restrict__ gmax, float* __restrict__ ginv)
{
    const int b = blockIdx.x, ch = threadIdx.x;
    const size_t base = (size_t)b * 32 * 256 + ch;
    float M = -3.4e38f;
    for (int c = 0; c < 32; ++c) M = fmaxf(M, pmax[base + (size_t)c * 256]);
    float s = 0.f;
    for (int c = 0; c < 32; ++c)
        s += psum[base + (size_t)c * 256] * __expf(pmax[base + (size_t)c * 256] - M);
    gmax[(size_t)b * 256 + ch] = M;
    ginv[(size_t)b * 256 + ch] = 1.f / s;
}

__global__ __launch_bounds__(256) void vsm_write(
    u16* __restrict__ vb, const float* __restrict__ gmax, const float* __restrict__ ginv)
{
    const int b = blockIdx.y, chunk = blockIdx.x, ch = threadIdx.x;
    u16* T = vb + ((size_t)b * 4096 + (size_t)chunk * 128) * 256 + ch;
    const float M = gmax[(size_t)b * 256 + ch], R = ginv[(size_t)b * 256 + ch];
    for (int r = 0; r < 128; ++r) {
        float x = bf2f(T[(size_t)r * 256]);
        T[(size_t)r * 256] = f2bf(__expf(x - M) * R);
    }
}

// ---------------------------------------------------------------------------
// 3) G split-K: grid (2, 2, 128); z = b*8 + kc, chunk K = 512.
//    Gpart[z][v][d] = sum_{n in chunk} ksmT[v][n] * qT[d][n]   (fp32)
// ---------------------------------------------------------------------------
__global__ __launch_bounds__(256) void g_gemm(
    const u16* __restrict__ kT, const u16* __restrict__ qT, float* __restrict__ Gpart)
{
    __shared__ u16 smem[8192];
    const int z = blockIdx.z, b = z >> 3, kc = z & 7;
    const int n0 = blockIdx.x * 128, m0 = blockIdx.y * 128;

    f32x4 acc[4][4];
#pragma unroll
    for (int i = 0; i < 4; ++i)
#pragma unroll
        for (int j = 0; j < 4; ++j) acc[i][j] = (f32x4){0.f, 0.f, 0.f, 0.f};

    gemm_core(kT + (size_t)b * (256 * 4096), 4096,
              qT + (size_t)b * (256 * 4096), 4096,
              m0, n0, (long)kc * 512, 16, smem, smem + 4096, acc);

    float* C = Gpart + (size_t)z * 65536;
    const int lane = threadIdx.x & 63, wave = threadIdx.x >> 6;
    const int wm = wave >> 1, wn = wave & 1, fr = lane & 15, kq = lane >> 4;
#pragma unroll
    for (int i = 0; i < 4; ++i)
#pragma unroll
        for (int j = 0; j < 4; ++j)
#pragma unroll
            for (int r = 0; r < 4; ++r) {
                const int row = wm * 64 + i * 16 + kq * 4 + r;
                const int col = wn * 64 + j * 16 + fr;
                C[(size_t)(m0 + row) * 256 + n0 + col] = acc[i][j][r];
            }
}

__global__ __launch_bounds__(256) void greduce(const float* __restrict__ Gpart,
                                               u16* __restrict__ Gb)
{
    const int i = blockIdx.x * 256 + threadIdx.x;   // grid = 4096 blocks exact
    const int b = i >> 16, r = i & 65535;
    const float* p = Gpart + (size_t)(b * 8) * 65536 + r;
    float s = 0.f;
#pragma unroll
    for (int kc = 0; kc < 8; ++kc) s += p[(size_t)kc * 65536];
    Gb[i] = f2bf(s);
}

// ---------------------------------------------------------------------------
// 4) GWT[b][c][v] = sum_d WrT[c][d] * Gb[b][v][d]  (== (G@Wr)^T), bf16 out.
//    grid (2, 4, 16).
// ---------------------------------------------------------------------------
__global__ __launch_bounds__(256) void gwT_gemm(
    const u16* __restrict__ WrT, const u16* __restrict__ Gb, u16* __restrict__ GWT)
{
    __shared__ u16 smem[8192];
    const int b = blockIdx.z;
    const int n0 = blockIdx.x * 128, m0 = blockIdx.y * 128;

    f32x4 acc[4][4];
#pragma unroll
    for (int i = 0; i < 4; ++i)
#pragma unroll
        for (int j = 0; j < 4; ++j) acc[i][j] = (f32x4){0.f, 0.f, 0.f, 0.f};

    gemm_core(WrT, 256, Gb + (size_t)b * 65536, 256, m0, n0, 0, 8,
              smem, smem + 4096, acc);

    u16* C = GWT + (size_t)b * (512 * 256);
    const int lane = threadIdx.x & 63, wave = threadIdx.x >> 6;
    const int wm = wave >> 1, wn = wave & 1, fr = lane & 15, kq = lane >> 4;
#pragma unroll
    for (int i = 0; i < 4; ++i)
#pragma unroll
        for (int j = 0; j < 4; ++j)
#pragma unroll
            for (int r = 0; r < 4; ++r) {
                const int row = wm * 64 + i * 16 + kq * 4 + r;
                const int col = wn * 64 + j * 16 + fr;
                C[(size_t)(m0 + row) * 256 + n0 + col] = f2bf(acc[i][j][r]);
            }
}

// ---------------------------------------------------------------------------
// 5) out[m][c] = sum_v vsm[m][v] * GWT[b][c][v] + br[c], fp32 out.
//    grid (4, 512); b = m0>>12.
// ---------------------------------------------------------------------------
__global__ __launch_bounds__(256) void out_gemm(
    const u16* __restrict__ vsm, const u16* __restrict__ GWT,
    const float* __restrict__ br, float* __restrict__ out)
{
    __shared__ u16 smem[8192];
    const int n0 = blockIdx.x * 128, m0 = blockIdx.y * 128;
    const int b = m0 >> 12;

    f32x4 acc[4][4];
#pragma unroll
    for (int i = 0; i < 4; ++i)
#pragma unroll
        for (int j = 0; j < 4; ++j) acc[i][j] = (f32x4){0.f, 0.f, 0.f, 0.f};

    gemm_core(vsm, 256, GWT + (size_t)b * (512 * 256), 256, m0, n0, 0, 8,
              smem, smem + 4096, acc);

    const int lane = threadIdx.x & 63, wave = threadIdx.x >> 6;
    const int wm = wave >> 1, wn = wave & 1, fr = lane & 15, kq = lane >> 4;
#pragma unroll
    for (int i = 0; i < 4; ++i)
#pragma unroll
        for (int j = 0; j < 4; ++j) {
            const int col = wn * 64 + j * 16 + fr;
            const float bias = br[n0 + col];
#pragma unroll
            for (int r = 0; r < 4; ++r) {
                const int row = wm * 64 + i * 16 + kq * 4 + r;
                out[(size_t)(m0 + row) * 512 + n0 + col] = acc[i][j][r] + bias;
            }
        }
}

// ---------------------------------------------------------------------------
extern "C" void kernel_launch(void* const* d_in, const int* in_sizes, int n_in,
                              void* d_out, int out_size, void* d_ws, size_t ws_size,
                              hipStream_t stream)
{
    const float* x  = (const float*)d_in[0];
    const float* Wq = (const float*)d_in[1];
    const float* bq = (const float*)d_in[2];
    const float* Wk = (const float*)d_in[3];
    const float* bk = (const float*)d_in[4];
    const float* Wv = (const float*)d_in[5];
    const float* bv = (const float*)d_in[6];
    const float* Wr = (const float*)d_in[7];
    const float* br = (const float*)d_in[8];
    float* out = (float*)d_out;

    // Workspace layout (bytes), total ~210 MB.
    char* w = (char*)d_ws;
    u16*   xb    = (u16*)(w);                       // 67,108,864
    u16*   qT    = (u16*)(w + 67108864);            // 33,554,432
    u16*   kT    = (u16*)(w + 100663296);           // 33,554,432
    u16*   vb    = (u16*)(w + 134217728);           // 33,554,432
    float* Gpart = (float*)(w + 167772160);         // 33,554,432
    u16*   Gb    = (u16*)(w + 201326592);           //  2,097,152
    u16*   GWT   = (u16*)(w + 203423744);           //  4,194,304
    u16*   WqkvT = (u16*)(w + 207618048);           //    786,432
    u16*   WrT   = (u16*)(w + 208404480);           //    262,144
    float* bqkv  = (float*)(w + 208666624);         //      3,072
    float* pmax  = (float*)(w + 208669696);         //    524,288
    float* psum  = (float*)(w + 209193984);         //    524,288
    float* gmax  = (float*)(w + 209718272);         //     16,384
    float* ginv  = (float*)(w + 209734656);         //     16,384

    const dim3 blk(256);

    // 0) casts
    cast_x<<<2048, blk, 0, stream>>>(x, xb, (MTOT * CDIM) / 4);
    cast_w<<<512, blk, 0, stream>>>(Wq, Wk, Wv, bq, bk, bv, Wr, WqkvT, WrT, bqkv);

    // 1) fused QKV projection (writes qT, kT transposed; vb direct)
    proj_qkv<<<dim3(6, 512), blk, 0, stream>>>(xb, WqkvT, bqkv, qT, kT, vb);

    // 2) softmaxes
    ksoftmax<<<BATCH * 256, blk, 0, stream>>>(kT);
    vsm_partial<<<dim3(32, BATCH), blk, 0, stream>>>(vb, pmax, psum);
    vsm_combine<<<BATCH, blk, 0, stream>>>(pmax, psum, gmax, ginv);
    vsm_write<<<dim3(32, BATCH), blk, 0, stream>>>(vb, gmax, ginv);

    // 3) G = ksm^T @ q, split-K=8 -> reduce+cast
    g_gemm<<<dim3(2, 2, BATCH * 8), blk, 0, stream>>>(kT, qT, Gpart);
    greduce<<<4096, blk, 0, stream>>>(Gpart, Gb);

    // 4) GWT = (G@Wr)^T  (bf16)
    gwT_gemm<<<dim3(2, 4, BATCH), blk, 0, stream>>>(WrT, Gb, GWT);

    // 5) out = vsm @ GW + br  (fp32)
    out_gemm<<<dim3(4, 512), blk, 0, stream>>>(vb, GWT, br, out);
}

// Round 3
// 426.631 us; speedup vs baseline: 2.9944x; 1.0889x over previous
//
#include <hip/hip_runtime.h>

// Double Attention (A^2-Net), bf16-MFMA, counted-vmcnt pipelined GEMMs.
// B=16, H=W=64, C=512, DIM=VDIM=256, N=4096.
//
// GEMM core: 128x128 tile, BK=32, 4 waves, double-buffered LDS (32KB),
// raw s_barrier + counted s_waitcnt vmcnt(4) (T3/T4), XOR-swizzled staging
// (pre-swizzled global source + swizzled frag read; LDS dest linear, rule #21),
// mfma_f32_16x16x32_bf16.
//
// Pipeline:
//  0) cast x -> xb (bf16); build WqkvT[768][512], WrT[512][256], bqkv
//  1) proj: -> qT/kT [b][256][4096] (XOR-skew LDS transpose epi), vb [n][256]
//  2) ksoftmax (rows of kT); vsoftmax (3-phase columns of vb)
//  3) g_gemm split-K=8 -> Gpart; greduce -> Gb (bf16)
//  4) gwT: GWT[b][512][256] = (G@Wr)^T
//  5) out: out = vsm @ GWT^T + br  (fused reconstruct)

#define BATCH 16
#define NPOS 4096
#define CDIM 512
#define DDIM 256
#define MTOT (BATCH * NPOS)

typedef unsigned short u16;
typedef __attribute__((ext_vector_type(4))) unsigned short u16x4;
typedef __attribute__((ext_vector_type(8))) unsigned short u16x8;
typedef __attribute__((ext_vector_type(8))) short s16x8;
typedef __attribute__((ext_vector_type(4))) float f32x4;

__device__ __forceinline__ u16 f2bf(float f) {
    union { float f; unsigned u; } v; v.f = f;
    unsigned u = v.u;
    unsigned r = (u + 0x7fffu + ((u >> 16) & 1u)) >> 16;
    return (u16)r;
}
__device__ __forceinline__ float bf2f(u16 h) {
    union { unsigned u; float f; } v; v.u = ((unsigned)h) << 16;
    return v.f;
}

__device__ __forceinline__ void gload_lds16(const u16* g, u16* l) {
    __builtin_amdgcn_global_load_lds(
        (const __attribute__((address_space(1))) void*)g,
        (__attribute__((address_space(3))) void*)l, 16, 0, 0);
}

// Stage one 128x32 A-tile + B-tile k-step into buffer (4 gload_lds per wave).
// Global source columns are pre-swizzled (slot ^ row&3) so that the
// swizzled READ pattern below sees linear-global data (involution).
__device__ __forceinline__ void stage_tile(
    const u16* Arow0, const u16* Arow1, const u16* Brow0, const u16* Brow1,
    u16* As, u16* Bs, int wave, long tko)
{
    gload_lds16(Arow0 + tko, As + wave * 512);
    gload_lds16(Arow1 + tko, As + 2048 + wave * 512);
    gload_lds16(Brow0 + tko, Bs + wave * 512);
    gload_lds16(Brow1 + tko, Bs + 2048 + wave * 512);
}

// ---------------------------------------------------------------------------
// Core 128x128 bf16 MFMA loop, counted-vmcnt double-buffered.
// smem: u16[16384] = buf0{A[4096],B[4096]}, buf1{A[4096],B[4096]}.
// Loop invariants (per wave): vmcnt(4)=buf[cur] staged, 4 newer in flight;
// lgkmcnt(0)+barrier before overwriting buf[cur] with tile t+2.
// ---------------------------------------------------------------------------
__device__ __forceinline__ void gemm_core(
    const u16* __restrict__ A, int lda,
    const u16* __restrict__ B, int ldb,
    int m0, int n0, long koff, int ksteps,
    u16* smem, f32x4 (&acc)[4][4])
{
    const int tid = threadIdx.x, lane = tid & 63, wave = tid >> 6;
    const int wm = wave >> 1, wn = wave & 1;
    const int fr = lane & 15, kq = lane >> 4;
    const int srow = lane >> 2, skq = lane & 3;
    const int sslot = (skq ^ (srow & 3)) * 8;     // source pre-swizzle

    const u16* Arow0 = A + (size_t)(m0 + wave * 16 + srow) * lda + koff + sslot;
    const u16* Arow1 = A + (size_t)(m0 + 64 + wave * 16 + srow) * lda + koff + sslot;
    const u16* Brow0 = B + (size_t)(n0 + wave * 16 + srow) * ldb + koff + sslot;
    const u16* Brow1 = B + (size_t)(n0 + 64 + wave * 16 + srow) * ldb + koff + sslot;

    u16* AsB[2] = { smem,        smem + 8192 };
    u16* BsB[2] = { smem + 4096, smem + 12288 };

    stage_tile(Arow0, Arow1, Brow0, Brow1, AsB[0], BsB[0], wave, 0);
    if (ksteps > 1)
        stage_tile(Arow0, Arow1, Brow0, Brow1, AsB[1], BsB[1], wave, 32);

    const int arow = wm * 64, brow = wn * 64;
    const int slot = (kq ^ (fr & 3)) * 8;         // swizzled read slot

    for (int t = 0; t < ksteps; ++t) {
        u16* As = AsB[t & 1];
        u16* Bs = BsB[t & 1];
        if (t + 1 < ksteps)
            asm volatile("s_waitcnt vmcnt(4)" ::: "memory");
        else
            asm volatile("s_waitcnt vmcnt(0)" ::: "memory");
        __builtin_amdgcn_s_barrier();             // buf[cur] staged by all waves

        s16x8 aF[4], bF[4];
#pragma unroll
        for (int i = 0; i < 4; ++i)
            aF[i] = *(const s16x8*)(As + (size_t)(arow + i * 16 + fr) * 32 + slot);
#pragma unroll
        for (int j = 0; j < 4; ++j)
            bF[j] = *(const s16x8*)(Bs + (size_t)(brow + j * 16 + fr) * 32 + slot);

        asm volatile("s_waitcnt lgkmcnt(0)" ::: "memory");
        __builtin_amdgcn_s_barrier();             // all waves' reads landed
        if (t + 2 < ksteps)                       // overwrite-safe prefetch
            stage_tile(Arow0, Arow1, Brow0, Brow1, As, Bs, wave, (long)(t + 2) * 32);

#pragma unroll
        for (int i = 0; i < 4; ++i)
#pragma unroll
            for (int j = 0; j < 4; ++j)
                acc[i][j] = __builtin_amdgcn_mfma_f32_16x16x32_bf16(
                    aF[i], bF[j], acc[i][j], 0, 0, 0);
    }
}

// ---------------------------------------------------------------------------
// 0) casts
// ---------------------------------------------------------------------------
__global__ __launch_bounds__(256) void cast_x(const float* __restrict__ x,
                                              u16* __restrict__ xb, int n4)
{
    int i = blockIdx.x * 256 + threadIdx.x;
    const int stride = gridDim.x * 256;
    for (; i < n4; i += stride) {
        float4 f = ((const float4*)x)[i];
        u16x4 o = { f2bf(f.x), f2bf(f.y), f2bf(f.z), f2bf(f.w) };
        ((u16x4*)xb)[i] = o;
    }
}

__global__ __launch_bounds__(256) void cast_w(
    const float* __restrict__ Wq, const float* __restrict__ Wk,
    const float* __restrict__ Wv, const float* __restrict__ bq,
    const float* __restrict__ bk, const float* __restrict__ bv,
    const float* __restrict__ Wr,
    u16* __restrict__ WqkvT, u16* __restrict__ WrT, float* __restrict__ bqkv)
{
    const int i0 = blockIdx.x * 256 + threadIdx.x;
    const int stride = gridDim.x * 256;
    for (int idx = i0; idx < 768 * 512; idx += stride) {
        int nc = idx >> 9, kk = idx & 511;
        const float* W = (nc < 256) ? Wq : (nc < 512) ? Wk : Wv;
        WqkvT[idx] = f2bf(W[(size_t)kk * 256 + (nc & 255)]);
    }
    for (int idx = i0; idx < 512 * 256; idx += stride) {
        int c = idx >> 8, d = idx & 255;
        WrT[idx] = f2bf(Wr[(size_t)d * 512 + c]);
    }
    for (int idx = i0; idx < 768; idx += stride)
        bqkv[idx] = (idx < 256) ? bq[idx] : (idx < 512) ? bk[idx - 256] : bv[idx - 512];
}

// LDS transpose-buffer skew: stride 64 u16/row, col XOR'd by (row>>2)&3 in
// 16-col blocks -> scalar u16 writes/reads hit every bank 2x (free).
__device__ __forceinline__ int tskew(int row, int col) {
    return row * 64 + (col ^ (((row >> 2) & 3) << 4));
}

// ---------------------------------------------------------------------------
// 1) fused QKV projection. 1D grid 3072, XCD-chunked swizzle (q=384).
//    decode: bx (0..5) = n-tile, by (0..511) = m-tile; mode = bx>>1.
// ---------------------------------------------------------------------------
__global__ __launch_bounds__(256) void proj_qkv(
    const u16* __restrict__ xb, const u16* __restrict__ WqkvT,
    const float* __restrict__ bqkv,
    u16* __restrict__ qT, u16* __restrict__ kT, u16* __restrict__ vb)
{
    __shared__ u16 smem[16384];   // 32KB: GEMM dbuf, then 4x 64x64 skewed Ts

    const int bid = blockIdx.x;
    const int nid = (bid & 7) * 384 + (bid >> 3);   // XCD-chunked (3072 = 8*384)
    const int bx = nid % 6;
    const int by = nid / 6;
    const int n0 = bx * 128;
    const int m0 = by * 128;

    f32x4 acc[4][4];
#pragma unroll
    for (int i = 0; i < 4; ++i)
#pragma unroll
        for (int j = 0; j < 4; ++j) acc[i][j] = (f32x4){0.f, 0.f, 0.f, 0.f};

    gemm_core(xb, 512, WqkvT, 512, m0, n0, 0, 16, smem, acc);

    const int tid = threadIdx.x, lane = tid & 63, wave = tid >> 6;
    const int wm = wave >> 1, wn = wave & 1, fr = lane & 15, kq = lane >> 4;
    const int mode = bx >> 1;
    const int nl0 = (bx & 1) * 128;

    if (mode == 2) {              // v: direct [n][v] bf16 store
#pragma unroll
        for (int i = 0; i < 4; ++i)
#pragma unroll
            for (int j = 0; j < 4; ++j) {
                const int col = wn * 64 + j * 16 + fr;
                const float bias = bqkv[n0 + col];
#pragma unroll
                for (int r = 0; r < 4; ++r) {
                    const int row = wm * 64 + i * 16 + kq * 4 + r;
                    vb[(size_t)(m0 + row) * 256 + nl0 + col] = f2bf(acc[i][j][r] + bias);
                }
            }
        return;
    }

    // q/k: skewed LDS-bounce transpose -> [channel][n] layout
    __syncthreads();                         // GEMM buffers dead, reuse as Ts
    u16* Ts = smem + wave * 4096;            // per-wave 64x64 skewed
#pragma unroll
    for (int i = 0; i < 4; ++i)
#pragma unroll
        for (int j = 0; j < 4; ++j) {
            const int colw = j * 16 + fr;
            const float bias = bqkv[n0 + wn * 64 + colw];
#pragma unroll
            for (int r = 0; r < 4; ++r)
                Ts[tskew(i * 16 + kq * 4 + r, colw)] = f2bf(acc[i][j][r] + bias);
        }
    __syncthreads();

    u16* dstT = (mode == 0) ? qT : kT;
    const int b = m0 >> 12;
    const int nbase = (m0 & 4095) + wm * 64;
    const int dch = nl0 + wn * 64 + lane;
    u16* dst = dstT + (size_t)b * (256 * 4096) + (size_t)dch * 4096 + nbase;
#pragma unroll
    for (int g = 0; g < 8; ++g) {
        u16x8 pack;
#pragma unroll
        for (int e = 0; e < 8; ++e)
            pack[e] = Ts[tskew(g * 8 + e, lane)];
        *(u16x8*)(dst + g * 8) = pack;
    }
}

// ---------------------------------------------------------------------------
// 2a) row softmax on kT. grid 4096 blocks.
// ---------------------------------------------------------------------------
__global__ __launch_bounds__(256) void ksoftmax(u16* __restrict__ kT)
{
    u16* row = kT + (size_t)blockIdx.x * 4096;
    const int t = threadIdx.x, lane = t & 63, wave = t >> 6;
    __shared__ float red[4];

    float x[16];
    u16x8 u0 = *(const u16x8*)(row + t * 16);
    u16x8 u1 = *(const u16x8*)(row + t * 16 + 8);
#pragma unroll
    for (int e = 0; e < 8; ++e) { x[e] = bf2f(u0[e]); x[8 + e] = bf2f(u1[e]); }

    float m = -3.4e38f;
#pragma unroll
    for (int e = 0; e < 16; ++e) m = fmaxf(m, x[e]);
    for (int off = 32; off; off >>= 1) m = fmaxf(m, __shfl_xor(m, off));
    if (lane == 0) red[wave] = m;
    __syncthreads();
    const float M = fmaxf(fmaxf(red[0], red[1]), fmaxf(red[2], red[3]));
    __syncthreads();

    float s = 0.f;
#pragma unroll
    for (int e = 0; e < 16; ++e) { x[e] = __expf(x[e] - M); s += x[e]; }
    for (int off = 32; off; off >>= 1) s += __shfl_xor(s, off);
    if (lane == 0) red[wave] = s;
    __syncthreads();
    const float inv = 1.f / (red[0] + red[1] + red[2] + red[3]);

    u16x8 o0, o1;
#pragma unroll
    for (int e = 0; e < 8; ++e) { o0[e] = f2bf(x[e] * inv); o1[e] = f2bf(x[8 + e] * inv); }
    *(u16x8*)(row + t * 16) = o0;
    *(u16x8*)(row + t * 16 + 8) = o1;
}

// ---------------------------------------------------------------------------
// 2b) column softmax on vb (3-phase).
// ---------------------------------------------------------------------------
__global__ __launch_bounds__(256) void vsm_partial(
    const u16* __restrict__ vb, float* __restrict__ pmax, float* __restrict__ psum)
{
    const int b = blockIdx.y, chunk = blockIdx.x, ch = threadIdx.x;
    const u16* T = vb + ((size_t)b * 4096 + (size_t)chunk * 128) * 256 + ch;
    float m = -3.4e38f, s = 0.f;
    for (int r = 0; r < 128; ++r) {
        float x = bf2f(T[(size_t)r * 256]);
        float nm = fmaxf(m, x);
        s = s * __expf(m - nm) + __expf(x - nm);
        m = nm;
    }
    const size_t idx = ((size_t)b * 32 + chunk) * 256 + ch;
    pmax[idx] = m; psum[idx] = s;
}

__global__ __launch_bounds__(256) void vsm_combine(
    const float* __restrict__ pmax, const float* __restrict__ psum,
    float* __restrict__ gmax, float* __restrict__ ginv)
{
    const int b = blockIdx.x, ch = threadIdx.x;
    const size_t base = (size_t)b * 32 * 256 + ch;
    float M = -3.4e38f;
    for (int c = 0; c < 32; ++c) M = fmaxf(M, pmax[base + (size_t)c * 256]);
    float s = 0.f;
    for (int c = 0; c < 32; ++c)
        s += psum[base + (size_t)c * 256] * __expf(pmax[base + (size_t)c * 256] - M);
    gmax[(size_t)b * 256 + ch] = M;
    ginv[(size_t)b * 256 + ch] = 1.f / s;
}

__global__ __launch_bounds__(256) void vsm_write(
    u16* __restrict__ vb, const float* __restrict__ gmax, const float* __restrict__ ginv)
{
    const int b = blockIdx.y, chunk = blockIdx.x, ch = threadIdx.x;
    u16* T = vb + ((size_t)b * 4096 + (size_t)chunk * 128) * 256 + ch;
    const float M = gmax[(size_t)b * 256 + ch], R = ginv[(size_t)b * 256 + ch];
    for (int r = 0; r < 128; ++r) {
        float x = bf2f(T[(size_t)r * 256]);
        T[(size_t)r * 256] = f2bf(__expf(x - M) * R);
    }
}

// ---------------------------------------------------------------------------
// 3) G split-K: grid (2, 2, 128); z = b*8 + kc, chunk K = 512.
// ---------------------------------------------------------------------------
__global__ __launch_bounds__(256) void g_gemm(
    const u16* __restrict__ kT, const u16* __restrict__ qT, float* __restrict__ Gpart)
{
    __shared__ u16 smem[16384];
    const int z = blockIdx.z, b = z >> 3, kc = z & 7;
    const int n0 = blockIdx.x * 128, m0 = blockIdx.y * 128;

    f32x4 acc[4][4];
#pragma unroll
    for (int i = 0; i < 4; ++i)
#pragma unroll
        for (int j = 0; j < 4; ++j) acc[i][j] = (f32x4){0.f, 0.f, 0.f, 0.f};

    gemm_core(kT + (size_t)b * (256 * 4096), 4096,
              qT + (size_t)b * (256 * 4096), 4096,
              m0, n0, (long)kc * 512, 16, smem, acc);

    float* C = Gpart + (size_t)z * 65536;
    const int lane = threadIdx.x & 63, wave = threadIdx.x >> 6;
    const int wm = wave >> 1, wn = wave & 1, fr = lane & 15, kq = lane >> 4;
#pragma unroll
    for (int i = 0; i < 4; ++i)
#pragma unroll
        for (int j = 0; j < 4; ++j)
#pragma unroll
            for (int r = 0; r < 4; ++r) {
                const int row = wm * 64 + i * 16 + kq * 4 + r;
                const int col = wn * 64 + j * 16 + fr;
                C[(size_t)(m0 + row) * 256 + n0 + col] = acc[i][j][r];
            }
}

__global__ __launch_bounds__(256) void greduce(const float* __restrict__ Gpart,
                                               u16* __restrict__ Gb)
{
    const int i = blockIdx.x * 256 + threadIdx.x;   // grid = 4096 exact
    const int b = i >> 16, r = i & 65535;
    const float* p = Gpart + (size_t)(b * 8) * 65536 + r;
    float s = 0.f;
#pragma unroll
    for (int kc = 0; kc < 8; ++kc) s += p[(size_t)kc * 65536];
    Gb[i] = f2bf(s);
}

// ---------------------------------------------------------------------------
// 4) GWT[b][c][v] = sum_d WrT[c][d] * Gb[b][v][d]. grid (2, 4, 16).
// ---------------------------------------------------------------------------
__global__ __launch_bounds__(256) void gwT_gemm(
    const u16* __restrict__ WrT, const u16* __restrict__ Gb, u16* __restrict__ GWT)
{
    __shared__ u16 smem[16384];
    const int b = blockIdx.z;
    const int n0 = blockIdx.x * 128, m0 = blockIdx.y * 128;

    f32x4 acc[4][4];
#pragma unroll
    for (int i = 0; i < 4; ++i)
#pragma unroll
        for (int j = 0; j < 4; ++j) acc[i][j] = (f32x4){0.f, 0.f, 0.f, 0.f};

    gemm_core(WrT, 256, Gb + (size_t)b * 65536, 256, m0, n0, 0, 8, smem, acc);

    u16* C = GWT + (size_t)b * (512 * 256);
    const int lane = threadIdx.x & 63, wave = threadIdx.x >> 6;
    const int wm = wave >> 1, wn = wave & 1, fr = lane & 15, kq = lane >> 4;
#pragma unroll
    for (int i = 0; i < 4; ++i)
#pragma unroll
        for (int j = 0; j < 4; ++j)
#pragma unroll
            for (int r = 0; r < 4; ++r) {
                const int row = wm * 64 + i * 16 + kq * 4 + r;
                const int col = wn * 64 + j * 16 + fr;
                C[(size_t)(m0 + row) * 256 + n0 + col] = f2bf(acc[i][j][r]);
            }
}

// ---------------------------------------------------------------------------
// 5) out = vsm @ GWT^T + br. 1D grid 2048, XCD-chunked swizzle (q=256).
// ---------------------------------------------------------------------------
__global__ __launch_bounds__(256) void out_gemm(
    const u16* __restrict__ vsm, const u16* __restrict__ GWT,
    const float* __restrict__ br, float* __restrict__ out)
{
    __shared__ u16 smem[16384];
    const int bid = blockIdx.x;
    const int nid = (bid & 7) * 256 + (bid >> 3);   // 2048 = 8*256
    const int n0 = (nid & 3) * 128;
    const int m0 = (nid >> 2) * 128;
    const int b = m0 >> 12;

    f32x4 acc[4][4];
#pragma unroll
    for (int i = 0; i < 4; ++i)
#pragma unroll
        for (int j = 0; j < 4; ++j) acc[i][j] = (f32x4){0.f, 0.f, 0.f, 0.f};

    gemm_core(vsm, 256, GWT + (size_t)b * (512 * 256), 256, m0, n0, 0, 8, smem, acc);

    const int lane = threadIdx.x & 63, wave = threadIdx.x >> 6;
    const int wm = wave >> 1, wn = wave & 1, fr = lane & 15, kq = lane >> 4;
#pragma unroll
    for (int i = 0; i < 4; ++i)
#pragma unroll
        for (int j = 0; j < 4; ++j) {
            const int col = wn * 64 + j * 16 + fr;
            const float bias = br[n0 + col];
#pragma unroll
            for (int r = 0; r < 4; ++r) {
                const int row = wm * 64 + i * 16 + kq * 4 + r;
                out[(size_t)(m0 + row) * 512 + n0 + col] = acc[i][j][r] + bias;
            }
        }
}

// ---------------------------------------------------------------------------
extern "C" void kernel_launch(void* const* d_in, const int* in_sizes, int n_in,
                              void* d_out, int out_size, void* d_ws, size_t ws_size,
                              hipStream_t stream)
{
    const float* x  = (const float*)d_in[0];
    const float* Wq = (const float*)d_in[1];
    const float* bq = (const float*)d_in[2];
    const float* Wk = (const float*)d_in[3];
    const float* bk = (const float*)d_in[4];
    const float* Wv = (const float*)d_in[5];
    const float* bv = (const float*)d_in[6];
    const float* Wr = (const float*)d_in[7];
    const float* br = (const float*)d_in[8];
    float* out = (float*)d_out;

    char* w = (char*)d_ws;
    u16*   xb    = (u16*)(w);                       // 67,108,864
    u16*   qT    = (u16*)(w + 67108864);            // 33,554,432
    u16*   kT    = (u16*)(w + 100663296);           // 33,554,432
    u16*   vb    = (u16*)(w + 134217728);           // 33,554,432
    float* Gpart = (float*)(w + 167772160);         // 33,554,432
    u16*   Gb    = (u16*)(w + 201326592);           //  2,097,152
    u16*   GWT   = (u16*)(w + 203423744);           //  4,194,304
    u16*   WqkvT = (u16*)(w + 207618048);           //    786,432
    u16*   WrT   = (u16*)(w + 208404480);           //    262,144
    float* bqkv  = (float*)(w + 208666624);         //      3,072
    float* pmax  = (float*)(w + 208669696);         //    524,288
    float* psum  = (float*)(w + 209193984);         //    524,288
    float* gmax  = (float*)(w + 209718272);         //     16,384
    float* ginv  = (float*)(w + 209734656);         //     16,384

    const dim3 blk(256);

    cast_x<<<2048, blk, 0, stream>>>(x, xb, (MTOT * CDIM) / 4);
    cast_w<<<512, blk, 0, stream>>>(Wq, Wk, Wv, bq, bk, bv, Wr, WqkvT, WrT, bqkv);

    proj_qkv<<<3072, blk, 0, stream>>>(xb, WqkvT, bqkv, qT, kT, vb);

    ksoftmax<<<BATCH * 256, blk, 0, stream>>>(kT);
    vsm_partial<<<dim3(32, BATCH), blk, 0, stream>>>(vb, pmax, psum);
    vsm_combine<<<BATCH, blk, 0, stream>>>(pmax, psum, gmax, ginv);
    vsm_write<<<dim3(32, BATCH), blk, 0, stream>>>(vb, gmax, ginv);

    g_gemm<<<dim3(2, 2, BATCH * 8), blk, 0, stream>>>(kT, qT, Gpart);
    greduce<<<4096, blk, 0, stream>>>(Gpart, Gb);

    gwT_gemm<<<dim3(2, 4, BATCH), blk, 0, stream>>>(WrT, Gb, GWT);

    out_gemm<<<2048, blk, 0, stream>>>(vb, GWT, br, out);
}